// Round 11
// baseline (124.066 us; speedup 1.0000x reference)
//
#include <hip/hip_runtime.h>

namespace {
constexpr int S = 1024, I = 512, C = 8, H = 8;
constexpr float LNEPS = 1e-5f;
constexpr float SCALE = 0.35355339059327373f; // 8^-0.5
}

__device__ __forceinline__ float dot8(const float x[8], float4 a, float4 b) {
    float r = x[0] * a.x;
    r += x[1] * a.y; r += x[2] * a.z; r += x[3] * a.w;
    r += x[4] * b.x; r += x[5] * b.y; r += x[6] * b.z; r += x[7] * b.w;
    return r;
}

__device__ __forceinline__ void ln8(float4 a, float4 b, const float gm[8],
                                    const float bt[8], float x[8]) {
    x[0] = a.x; x[1] = a.y; x[2] = a.z; x[3] = a.w;
    x[4] = b.x; x[5] = b.y; x[6] = b.z; x[7] = b.w;
    float mu = 0.f;
#pragma unroll
    for (int c = 0; c < 8; c++) mu += x[c];
    mu *= 0.125f;
    float var = 0.f;
#pragma unroll
    for (int c = 0; c < 8; c++) { float d = x[c] - mu; var += d * d; }
    var *= 0.125f;
    float inv = rsqrtf(var + LNEPS);
#pragma unroll
    for (int c = 0; c < 8; c++) x[c] = (x[c] - mu) * inv * gm[c] + bt[c];
}

// Kernel A: qk + rden only (phases 1-2 of the fused kernel).
// 256 blocks x 1024 threads, 2 cols/block, 2 rows/thread — proven shape.
__global__ __launch_bounds__(1024) void k_qkden(
    const float* __restrict__ m, const float* __restrict__ gamma,
    const float* __restrict__ beta, const float* __restrict__ Wq,
    const float* __restrict__ Wk, float* __restrict__ qk_g,
    float* __restrict__ rden_g) {
    __shared__ __align__(16) float swred[16 * 16]; // [wave][col*8+c]
    __shared__ __align__(16) float sxbar[16];      // [col][c]
    __shared__ __align__(16) float sqk[128];       // [col][h*8+c2]

    int t = threadIdx.x;
    int w = t >> 6;
    int col = t & 1;
    int si = t >> 1;          // [0,512)
    int i = 2 * blockIdx.x + col;

    float gm[8], bt[8];
#pragma unroll
    for (int c = 0; c < 8; c++) { gm[c] = gamma[c]; bt[c] = beta[c]; }

    // phase 1: LN + LN-sum
    const float4* m4 = (const float4*)m;
    float x[2][8];
    float acc[8];
#pragma unroll
    for (int c = 0; c < 8; c++) acc[c] = 0.f;
#pragma unroll
    for (int r = 0; r < 2; r++) {
        int row = (si + 512 * r) * I + i;
        ln8(m4[row * 2], m4[row * 2 + 1], gm, bt, x[r]);
#pragma unroll
        for (int c = 0; c < 8; c++) acc[c] += x[r][c];
    }
#pragma unroll
    for (int d = 2; d < 64; d <<= 1)
#pragma unroll
        for (int c = 0; c < 8; c++) acc[c] += __shfl_xor(acc[c], d, 64);
    if ((t & 63) < 2) {
#pragma unroll
        for (int c = 0; c < 8; c++) swred[w * 16 + col * 8 + c] = acc[c];
    }
    __syncthreads();   // S1
    if (t < 16) {
        float s = 0.f;
#pragma unroll
        for (int ww = 0; ww < 16; ww++) s += swred[ww * 16 + t];
        sxbar[t] = s;
    }
    __syncthreads();   // S2
    if (t < 128) {     // qk[col][h][c2]
        int qcol = t >> 6, h = (t >> 3) & 7, c2 = t & 7;
        float xb[8];
#pragma unroll
        for (int c3 = 0; c3 < 8; c3++) xb[c3] = sxbar[qcol * 8 + c3];
        float a = 0.f;
#pragma unroll
        for (int c = 0; c < 8; c++) {
            float qc = 0.f;
#pragma unroll
            for (int c3 = 0; c3 < 8; c3++)
                qc += xb[c3] * Wq[(h * 8 + c) * 8 + c3];
            a += qc * Wk[c * 8 + c2];
        }
        float val = a * (SCALE / 1024.0f);
        sqk[qcol * 64 + (t & 63)] = val;
        qk_g[(2 * blockIdx.x + qcol) * 64 + (t & 63)] = val;
    }
    __syncthreads();   // S3

    // phase 2: exp sums -> rden
    const float4* sqk4 = (const float4*)sqk;
    float e[8];
#pragma unroll
    for (int h = 0; h < 8; h++) {
        float4 q0 = sqk4[col * 16 + h * 2], q1 = sqk4[col * 16 + h * 2 + 1];
        float s = 0.f;
#pragma unroll
        for (int r = 0; r < 2; r++) s += __expf(dot8(x[r], q0, q1));
        e[h] = s;
    }
#pragma unroll
    for (int d = 2; d < 64; d <<= 1)
#pragma unroll
        for (int h = 0; h < 8; h++) e[h] += __shfl_xor(e[h], d, 64);
    if ((t & 63) < 2) {
#pragma unroll
        for (int h = 0; h < 8; h++) swred[w * 16 + col * 8 + h] = e[h];
    }
    __syncthreads();   // S4
    if (t < 16) {
        float s = 0.f;
#pragma unroll
        for (int ww = 0; ww < 16; ww++) s += swred[ww * 16 + t];
        rden_g[(2 * blockIdx.x + (t >> 3)) * 8 + (t & 7)] = 1.0f / s;
    }
}

// Kernel B: output contraction — embarrassingly parallel, high occupancy.
// 2048 blocks x 256 threads, 1 row/thread. Block (cp,rc) owns cols
// {2cp,2cp+1} x rows [rc*128,(rc+1)*128). Lane pairs keep 64B coalescing.
// Small live set (~60-70 VGPR, all static-indexed) -> 6-8 waves/SIMD.
__global__ __launch_bounds__(256) void k_out(
    const float* __restrict__ m, const float* __restrict__ gamma,
    const float* __restrict__ beta, const float* __restrict__ Wv,
    const float* __restrict__ Wg, const float* __restrict__ Wo,
    const float* __restrict__ bo, const float* __restrict__ qk_g,
    const float* __restrict__ rden_g, float* __restrict__ out) {
    __shared__ __align__(16) float sWoT[512];  // sWoT[j][c2] = Wo[c2][j]
    __shared__ __align__(16) float sqk[128];   // [col][h*8+c2]
    __shared__ __align__(16) float srd[16];    // [col][h]

    int t = threadIdx.x;
    int b = blockIdx.x;
    int cp = b >> 3;          // column pair [0,256)
    int rc = b & 7;           // row chunk [0,8)
    int col = t & 1;
    int i = 2 * cp + col;
    int s = rc * 128 + (t >> 1);

    // stage: WoT (2 elems/thread), qk (128), rden (16)
#pragma unroll
    for (int k = 0; k < 2; k++) {
        int idx = t + 256 * k;
        int j = idx & 63, c2 = idx >> 6;
        sWoT[j * 8 + c2] = Wo[c2 * 64 + j];
    }
    if (t < 128) sqk[t] = qk_g[cp * 128 + t];
    if (t < 16) srd[t] = rden_g[cp * 16 + t];
    __syncthreads();          // only barrier in this kernel

    float gm[8], bt[8];
#pragma unroll
    for (int c = 0; c < 8; c++) { gm[c] = gamma[c]; bt[c] = beta[c]; }

    const float4* m4 = (const float4*)m;
    float x[8];
    {
        int row = s * I + i;
        ln8(m4[row * 2], m4[row * 2 + 1], gm, bt, x);
    }

    // v[c] = x . Wv_c  (Wv uniform -> s_load)
    const float4* Wv4 = (const float4*)Wv;
    float v[8];
#pragma unroll
    for (int c = 0; c < 8; c++) v[c] = dot8(x, Wv4[c * 2], Wv4[c * 2 + 1]);

    // p[h] = exp(x . qk_h) * rden[h]   (bit-identical to kernel A's exps)
    const float4* sqk4 = (const float4*)sqk;
    float p[8];
#pragma unroll
    for (int h = 0; h < 8; h++) {
        float4 q0 = sqk4[col * 16 + h * 2], q1 = sqk4[col * 16 + h * 2 + 1];
        p[h] = __expf(dot8(x, q0, q1)) * srd[col * 8 + h];
    }

    float oacc[8];
#pragma unroll
    for (int c2 = 0; c2 < 8; c2++) oacc[c2] = bo[c2];

    const float4* Wg4 = (const float4*)Wg;
    const float4* sWoT4 = (const float4*)sWoT;
#pragma unroll
    for (int h = 0; h < 8; h++) {
#pragma unroll
        for (int c = 0; c < 8; c++) {
            int hc = h * 8 + c;
            float z = dot8(x, Wg4[hc * 2], Wg4[hc * 2 + 1]);
            float gate = __builtin_amdgcn_rcpf(1.0f + __expf(-z));
            float o_ = gate * p[h] * v[c];
            float4 wo0 = sWoT4[hc * 2], wo1 = sWoT4[hc * 2 + 1];
            oacc[0] += o_ * wo0.x; oacc[1] += o_ * wo0.y;
            oacc[2] += o_ * wo0.z; oacc[3] += o_ * wo0.w;
            oacc[4] += o_ * wo1.x; oacc[5] += o_ * wo1.y;
            oacc[6] += o_ * wo1.z; oacc[7] += o_ * wo1.w;
        }
    }
    float4* out4 = (float4*)out;
    int row = s * I + i;
    out4[row * 2] = make_float4(oacc[0], oacc[1], oacc[2], oacc[3]);
    out4[row * 2 + 1] = make_float4(oacc[4], oacc[5], oacc[6], oacc[7]);
}

extern "C" void kernel_launch(void* const* d_in, const int* in_sizes, int n_in,
                              void* d_out, int out_size, void* d_ws, size_t ws_size,
                              hipStream_t stream) {
    const float* m     = (const float*)d_in[0];
    const float* gamma = (const float*)d_in[1];
    const float* beta  = (const float*)d_in[2];
    const float* Wq    = (const float*)d_in[3];
    const float* Wk    = (const float*)d_in[4];
    const float* Wv    = (const float*)d_in[5];
    const float* Wg    = (const float*)d_in[6];
    const float* Wo    = (const float*)d_in[7];
    const float* bo    = (const float*)d_in[8];
    float* out = (float*)d_out;

    float* ws     = (float*)d_ws;
    float* qk_g   = ws;                         // I*64 floats = 128 KiB
    float* rden_g = ws + (size_t)I * 64;        // I*8 floats

    k_qkden<<<I / 2, 1024, 0, stream>>>(m, gamma, beta, Wq, Wk, qk_g, rden_g);
    k_out<<<2048, 256, 0, stream>>>(m, gamma, beta, Wv, Wg, Wo, bo, qk_g,
                                    rden_g, out);
}

// Round 12
// 106.470 us; speedup vs baseline: 1.1653x; 1.1653x over previous
//
#include <hip/hip_runtime.h>

namespace {
constexpr int S = 1024, I = 512, C = 8, H = 8;
constexpr int R = 2;                 // rows per thread (per its column)
constexpr float LNEPS = 1e-5f;
constexpr float SCALE = 0.35355339059327373f; // 8^-0.5
}

typedef float f32x2 __attribute__((ext_vector_type(2)));

__device__ __forceinline__ float dot8(const float x[8], float4 a, float4 b) {
    float r = x[0] * a.x;
    r += x[1] * a.y; r += x[2] * a.z; r += x[3] * a.w;
    r += x[4] * b.x; r += x[5] * b.y; r += x[6] * b.z; r += x[7] * b.w;
    return r;
}

// pairwise dot8 on f32x2 lanes: acc.x = x0w0+x2w2+x4w4+x6w6, .y = odd terms.
// Contracts to v_pk_fma_f32 (ffp-contract=fast on <2 x float>).
__device__ __forceinline__ float dot8p(const f32x2 x2[4], float4 a, float4 b) {
    f32x2 w0; w0.x = a.x; w0.y = a.y;
    f32x2 w1; w1.x = a.z; w1.y = a.w;
    f32x2 w2; w2.x = b.x; w2.y = b.y;
    f32x2 w3; w3.x = b.z; w3.y = b.w;
    f32x2 acc = x2[0] * w0;
    acc = x2[1] * w1 + acc;
    acc = x2[2] * w2 + acc;
    acc = x2[3] * w3 + acc;
    return acc.x + acc.y;
}

__device__ __forceinline__ void ln8(float4 a, float4 b, const float gm[8],
                                    const float bt[8], float x[8]) {
    x[0] = a.x; x[1] = a.y; x[2] = a.z; x[3] = a.w;
    x[4] = b.x; x[5] = b.y; x[6] = b.z; x[7] = b.w;
    float mu = 0.f;
#pragma unroll
    for (int c = 0; c < 8; c++) mu += x[c];
    mu *= 0.125f;
    float var = 0.f;
#pragma unroll
    for (int c = 0; c < 8; c++) { float d = x[c] - mu; var += d * d; }
    var *= 0.125f;
    float inv = rsqrtf(var + LNEPS);
#pragma unroll
    for (int c = 0; c < 8; c++) x[c] = (x[c] - mu) * inv * gm[c] + bt[c];
}

// 256 blocks x 1024 threads, 2 columns/block, 2 rows/thread (R10 geometry —
// best verified: 111.3 total). This rev: phase-2/3 math re-expressed as
// f32x2 packed ops so the Wo accumulation (4 pk_fma vs 8 fma) and the
// gate/v/p dots contract to v_pk_fma_f32 — ~35% fewer VALU issue slots.
// Grid == CU count -> 1 block/CU = 16 waves/CU regardless of VGPR (<=512).
__global__ __launch_bounds__(1024) void fused(
    const float* __restrict__ m, const float* __restrict__ gamma,
    const float* __restrict__ beta, const float* __restrict__ Wq,
    const float* __restrict__ Wk, const float* __restrict__ Wv,
    const float* __restrict__ Wg, const float* __restrict__ Wo,
    const float* __restrict__ bo, float* __restrict__ out) {
    __shared__ __align__(16) float sWoT[512];      // sWoT[j][c2] = Wo[c2][j]
    __shared__ __align__(16) float swred[16 * 16]; // [wave][col*8+c]
    __shared__ __align__(16) float sxbar[16];      // [col][c]
    __shared__ __align__(16) float sqk[128];       // [col][h*8+c2]
    __shared__ __align__(16) float srden[16];      // [col][h]

    int t = threadIdx.x;
    int w = t >> 6;          // wave id [0,16)
    int col = t & 1;         // which of the block's 2 columns
    int si = t >> 1;         // [0,512): s = si + 512*r
    int i = 2 * blockIdx.x + col;

    // ---- stage transposed Wo ----
    if (t < 512) {
        int j = t & 63, c2 = t >> 6;
        sWoT[j * 8 + c2] = Wo[c2 * 64 + j];
    }

    float gm[8], bt[8];
#pragma unroll
    for (int c = 0; c < 8; c++) { gm[c] = gamma[c]; bt[c] = beta[c]; }

    // ---- phase 1: load m once, LN, per-thread LN-sum ----
    const float4* m4 = (const float4*)m;
    float x[R][8];
    float acc[8];
#pragma unroll
    for (int c = 0; c < 8; c++) acc[c] = 0.f;
#pragma unroll
    for (int r = 0; r < R; r++) {
        int row = (si + 512 * r) * I + i;
        ln8(m4[row * 2], m4[row * 2 + 1], gm, bt, x[r]);
#pragma unroll
        for (int c = 0; c < 8; c++) acc[c] += x[r][c];
    }
    // packed pairs of x for phase 2/3 dots: x2[r][j] = {x[2j], x[2j+1]}
    f32x2 x2[R][4];
#pragma unroll
    for (int r = 0; r < R; r++)
#pragma unroll
        for (int j = 0; j < 4; j++) {
            x2[r][j].x = x[r][2 * j]; x2[r][j].y = x[r][2 * j + 1];
        }

    // parity-preserving wave reduce (keeps col separate)
#pragma unroll
    for (int d = 2; d < 64; d <<= 1)
#pragma unroll
        for (int c = 0; c < 8; c++) acc[c] += __shfl_xor(acc[c], d, 64);
    if ((t & 63) < 2) {
#pragma unroll
        for (int c = 0; c < 8; c++) swred[w * 16 + col * 8 + c] = acc[c];
    }
    __syncthreads();   // S1 (also covers sWoT staging)
    if (t < 16) {      // col = t>>3, c = t&7
        float s = 0.f;
#pragma unroll
        for (int ww = 0; ww < 16; ww++) s += swred[ww * 16 + t];
        sxbar[t] = s;
    }
    __syncthreads();   // S2
    // qk[col][h][c2] = SCALE/S * sum_c (xbar . Wq_hc) Wk[c][c2]
    if (t < 128) {
        int qcol = t >> 6, h = (t >> 3) & 7, c2 = t & 7;
        float xb[8];
#pragma unroll
        for (int c3 = 0; c3 < 8; c3++) xb[c3] = sxbar[qcol * 8 + c3];
        float a = 0.f;
#pragma unroll
        for (int c = 0; c < 8; c++) {
            float qc = 0.f;
#pragma unroll
            for (int c3 = 0; c3 < 8; c3++)
                qc += xb[c3] * Wq[(h * 8 + c) * 8 + c3];
            a += qc * Wk[c * 8 + c2];
        }
        sqk[qcol * 64 + h * 8 + c2] = a * (SCALE / 1024.0f);
    }
    __syncthreads();   // S3

    // ---- phase 2: exp logits cached in p (static idx) + denominator ----
    const float4* sqk4 = (const float4*)sqk;
    float p[R][8];
    {
        float e[8];
#pragma unroll
        for (int h = 0; h < 8; h++) {
            float4 q0 = sqk4[col * 16 + h * 2], q1 = sqk4[col * 16 + h * 2 + 1];
            float s = 0.f;
#pragma unroll
            for (int r = 0; r < R; r++) {
                p[r][h] = __expf(dot8p(x2[r], q0, q1));
                s += p[r][h];
            }
            e[h] = s;
        }
#pragma unroll
        for (int d = 2; d < 64; d <<= 1)
#pragma unroll
            for (int h = 0; h < 8; h++) e[h] += __shfl_xor(e[h], d, 64);
        if ((t & 63) < 2) {
#pragma unroll
            for (int h = 0; h < 8; h++) swred[w * 16 + col * 8 + h] = e[h];
        }
    }
    __syncthreads();   // S4
    if (t < 16) {
        float s = 0.f;
#pragma unroll
        for (int ww = 0; ww < 16; ww++) s += swred[ww * 16 + t];
        srden[t] = 1.0f / s;
    }
    __syncthreads();   // S5

    // pre-scale p by 1/denominator (LDS read, static p idx)
#pragma unroll
    for (int h = 0; h < 8; h++) {
        float rd = srden[col * 8 + h];
#pragma unroll
        for (int r = 0; r < R; r++) p[r][h] *= rd;
    }

    // ---- phase 3: FULLY unrolled, f32x2-packed output contraction ----
    const float4* Wv4 = (const float4*)Wv;
    const float4* Wg4 = (const float4*)Wg;
    const f32x2* sWoT2 = (const f32x2*)sWoT;

    f32x2 oacc2[R][4];
#pragma unroll
    for (int r = 0; r < R; r++)
#pragma unroll
        for (int j = 0; j < 4; j++) {
            oacc2[r][j].x = bo[2 * j]; oacc2[r][j].y = bo[2 * j + 1];
        }

#pragma unroll
    for (int c = 0; c < 8; c++) {
        float4 wv0 = Wv4[c * 2], wv1 = Wv4[c * 2 + 1];
        float vr[R];
#pragma unroll
        for (int r = 0; r < R; r++) vr[r] = dot8p(x2[r], wv0, wv1);
#pragma unroll
        for (int h = 0; h < 8; h++) {
            int hc = h * 8 + c;
            float4 wg0 = Wg4[hc * 2], wg1 = Wg4[hc * 2 + 1];
            f32x2 wo0 = sWoT2[hc * 4 + 0], wo1 = sWoT2[hc * 4 + 1];
            f32x2 wo2 = sWoT2[hc * 4 + 2], wo3 = sWoT2[hc * 4 + 3];
#pragma unroll
            for (int r = 0; r < R; r++) {
                float z = dot8p(x2[r], wg0, wg1);
                float gate = __builtin_amdgcn_rcpf(1.0f + __expf(-z));
                float o_ = gate * p[r][h] * vr[r];
                f32x2 o2; o2.x = o_; o2.y = o_;
                oacc2[r][0] = o2 * wo0 + oacc2[r][0];   // v_pk_fma_f32
                oacc2[r][1] = o2 * wo1 + oacc2[r][1];
                oacc2[r][2] = o2 * wo2 + oacc2[r][2];
                oacc2[r][3] = o2 * wo3 + oacc2[r][3];
            }
        }
    }
    float4* out4 = (float4*)out;
#pragma unroll
    for (int r = 0; r < R; r++) {
        int row = (si + 512 * r) * I + i;
        out4[row * 2] = make_float4(oacc2[r][0].x, oacc2[r][0].y,
                                    oacc2[r][1].x, oacc2[r][1].y);
        out4[row * 2 + 1] = make_float4(oacc2[r][2].x, oacc2[r][2].y,
                                        oacc2[r][3].x, oacc2[r][3].y);
    }
}

extern "C" void kernel_launch(void* const* d_in, const int* in_sizes, int n_in,
                              void* d_out, int out_size, void* d_ws, size_t ws_size,
                              hipStream_t stream) {
    const float* m     = (const float*)d_in[0];
    const float* gamma = (const float*)d_in[1];
    const float* beta  = (const float*)d_in[2];
    const float* Wq    = (const float*)d_in[3];
    const float* Wk    = (const float*)d_in[4];
    const float* Wv    = (const float*)d_in[5];
    const float* Wg    = (const float*)d_in[6];
    const float* Wo    = (const float*)d_in[7];
    const float* bo    = (const float*)d_in[8];
    float* out = (float*)d_out;

    fused<<<I / 2, 1024, 0, stream>>>(m, gamma, beta, Wq, Wk, Wv, Wg, Wo, bo, out);
}